// Round 2
// baseline (318.319 us; speedup 1.0000x reference)
//
#include <hip/hip_runtime.h>

typedef unsigned short ushort_t;
typedef unsigned int uint_t;
typedef __attribute__((ext_vector_type(8))) short v8s;   // 8 x bf16 (4 VGPRs)
typedef __attribute__((ext_vector_type(4))) float v4f;   // MFMA accumulator / float4

#define BN_SCALE 0.9999950000374997f

__device__ __forceinline__ float bf2f(ushort_t u) {
    union { uint_t i; float f; } v;
    v.i = ((uint_t)u) << 16;
    return v.f;
}
__device__ __forceinline__ ushort_t f2bf(float f) {
    union { uint_t i; float f; } v;
    v.f = f;
    uint_t b = v.i;
    b += 0x7fffu + ((b >> 16) & 1u);   // RNE
    return (ushort_t)(b >> 16);
}

// ---------------------------------------------------------------------------
// Kernel 1: cur0[n][d] = src_feats[n] . fc0_w[d] + fc0_b[d]  (and cur1),
// stored as bf16 (consumed by the MFMA path, which rounds to bf16 anyway).
// Block: 256 threads, 32 rows per block. LDS-transposed weights.
// ---------------------------------------------------------------------------
__global__ __launch_bounds__(256) void cur_kernel(
    const float* __restrict__ src_feats,                     // (N,64) f32
    const float* __restrict__ fc0_w, const float* __restrict__ fc0_b,
    const float* __restrict__ fc1_w, const float* __restrict__ fc1_b,
    ushort_t* __restrict__ cur0, ushort_t* __restrict__ cur1)
{
    __shared__ float w0T[64 * 66];
    __shared__ float w1T[64 * 66];
    __shared__ float rows[32 * 65];

    const int tid = threadIdx.x;
    const int n0 = blockIdx.x * 32;

    for (int e = tid; e < 4096; e += 256) {
        int dd = e >> 6, cc = e & 63;
        w0T[cc * 66 + dd] = fc0_w[e];
        w1T[cc * 66 + dd] = fc1_w[e];
    }
    for (int e = tid; e < 2048; e += 256) {
        int r = e >> 6, c = e & 63;
        rows[r * 65 + c] = src_feats[(n0 + r) * 64 + c];
    }
    __syncthreads();

    const int d = tid & 63;
    const int q = tid >> 6;
    const float b0 = fc0_b[d];
    const float b1 = fc1_b[d];

    for (int t = 0; t < 8; ++t) {
        const int r = q + 4 * t;
        float a0 = b0, a1 = b1;
        #pragma unroll
        for (int c = 0; c < 64; ++c) {
            const float f = rows[r * 65 + c];
            a0 = fmaf(f, w0T[c * 66 + d], a0);
            a1 = fmaf(f, w1T[c * 66 + d], a1);
        }
        cur0[(n0 + r) * 64 + d] = f2bf(a0);
        cur1[(n0 + r) * 64 + d] = f2bf(a1);
    }
}

// ---------------------------------------------------------------------------
// Kernel 2/3: SA layer. 16 dst points per block, 256 threads (4 waves).
// Phase A: x[s][d] = silu(bn(p_w . feat6)) + cur[idx[s]][d], masked -> LDS bf16
// Phase B: (S x 64) @ (64 x 128) via mfma_f32_16x16x32_bf16, bn+relu+max_s.
// m_w fragments (fp32 -> bf16) built once per block; xlds rows padded to
// 72 ushorts (144 B, 16B-aligned) to break b128 read bank conflicts.
// ---------------------------------------------------------------------------
template <int S>
__global__ __launch_bounds__(256) void sa_kernel(
    const float* __restrict__ src_xyz,   // (N,3) f32
    const float* __restrict__ dst_xyz,   // (M,3) f32
    const int*   __restrict__ idx,       // (M,S)
    const int*   __restrict__ empty,     // (M,)
    const float* __restrict__ p_w,       // (64,6)
    const float* __restrict__ p_g,
    const float* __restrict__ p_b,
    const float* __restrict__ m_w,       // (128,64)
    const float* __restrict__ m_g,
    const float* __restrict__ m_b,
    const ushort_t* __restrict__ cur,    // (N,64) bf16
    float*       __restrict__ f01,       // (M,256) f32
    int layer_off)
{
    constexpr int MPB = 16;
    constexpr int XP  = 72;              // padded row stride (ushorts)
    __shared__ ushort_t xlds[S * XP];

    const int tid  = threadIdx.x;
    const int lane = tid & 63;
    const int wid  = tid >> 6;           // 0..3
    const int m0   = blockIdx.x * MPB;

    // ---- phase-A per-thread constants (d = lane) ----
    const int d = lane;
    float pw[6];
    #pragma unroll
    for (int c = 0; c < 6; ++c) pw[c] = p_w[d * 6 + c];
    const float pg = p_g[d] * BN_SCALE;
    const float pb = p_b[d];

    // ---- phase-B per-wave constants ----
    const int col  = lane & 15;
    const int quad = lane >> 4;
    v8s bfrag[2][2];                     // [ct][kf]
    float mgv[2], mbv[2];
    #pragma unroll
    for (int c = 0; c < 2; ++c) {
        const int h = (wid * 2 + c) * 16 + col;
        #pragma unroll
        for (int kf = 0; kf < 2; ++kf) {
            const float* wp = m_w + h * 64 + kf * 32 + quad * 8;
            v8s f;
            #pragma unroll
            for (int j = 0; j < 8; ++j) f[j] = (short)f2bf(wp[j]);
            bfrag[c][kf] = f;
        }
        mgv[c] = m_g[h] * BN_SCALE;
        mbv[c] = m_b[h];
    }

    for (int mi = 0; mi < MPB; ++mi) {
        const int m = m0 + mi;
        // ================= phase A =================
        const int   em  = empty[m];
        const float dpx = dst_xyz[m * 3 + 0];
        const float dpy = dst_xyz[m * 3 + 1];
        const float dpz = dst_xyz[m * 3 + 2];
        #pragma unroll
        for (int t = 0; t < S / 4; ++t) {
            const int s = wid + 4 * t;                 // wave-uniform s
            const int i = idx[m * S + s];
            const float f0 = src_xyz[i * 3 + 0] - dpx;
            const float f1 = src_xyz[i * 3 + 1] - dpy;
            const float f2 = src_xyz[i * 3 + 2] - dpz;
            float off = fmaf(pw[0], f0,
                        fmaf(pw[1], f1,
                        fmaf(pw[2], f2,
                        fmaf(pw[3], dpx,
                        fmaf(pw[4], dpy, pw[5] * dpz)))));
            const float v   = fmaf(off, pg, pb);
            const float sil = v / (1.0f + __expf(-v));
            float x = sil + bf2f(cur[i * 64 + d]);
            x = em ? 0.0f : x;
            xlds[s * XP + d] = f2bf(x);
        }
        __syncthreads();

        // ================= phase B =================
        v4f acc[S / 16][2];
        #pragma unroll
        for (int rt = 0; rt < S / 16; ++rt)
            #pragma unroll
            for (int c = 0; c < 2; ++c)
                acc[rt][c] = (v4f)0.0f;

        #pragma unroll
        for (int rt = 0; rt < S / 16; ++rt) {
            #pragma unroll
            for (int kf = 0; kf < 2; ++kf) {
                const v8s afrag =
                    *(const v8s*)(xlds + (rt * 16 + col) * XP + kf * 32 + quad * 8);
                acc[rt][0] = __builtin_amdgcn_mfma_f32_16x16x32_bf16(
                    afrag, bfrag[0][kf], acc[rt][0], 0, 0, 0);
                acc[rt][1] = __builtin_amdgcn_mfma_f32_16x16x32_bf16(
                    afrag, bfrag[1][kf], acc[rt][1], 0, 0, 0);
            }
        }

        // epilogue: bn, relu, max over s (C/D layout: col=lane&15, row=quad*4+r)
        float vmax0 = 0.0f, vmax1 = 0.0f;
        #pragma unroll
        for (int c = 0; c < 2; ++c) {
            float vm = 0.0f;   // relu(y)>=0, so 0 is a valid identity
            #pragma unroll
            for (int rt = 0; rt < S / 16; ++rt)
                #pragma unroll
                for (int r = 0; r < 4; ++r) {
                    const float y = fmaf(acc[rt][c][r], mgv[c], mbv[c]);
                    vm = fmaxf(vm, y);
                }
            vm = fmaxf(vm, __shfl_xor(vm, 16));
            vm = fmaxf(vm, __shfl_xor(vm, 32));
            if (c == 0) vmax0 = vm; else vmax1 = vm;
        }
        if (lane < 32) {
            const int c = lane >> 4;
            const float val = (c == 0) ? vmax0 : vmax1;
            f01[m * 256 + layer_off + (wid * 2 + c) * 16 + (lane & 15)] = val;
        }
        __syncthreads();   // protect xlds before next m overwrites it
    }
}

// ---------------------------------------------------------------------------
// Kernel 4: out[m][o] = relu(bn(f01[m] . out_w[o]))  -- 16 rows per block,
// thread-per-column, f-tile broadcast from LDS as float4. fp32 in/out.
// ---------------------------------------------------------------------------
__global__ __launch_bounds__(256) void out_kernel(
    const float* __restrict__ f01,     // (M,256) f32
    const float* __restrict__ out_w,   // (256,256) f32
    const float* __restrict__ out_g,
    const float* __restrict__ out_b,
    float*       __restrict__ out)     // (M,256) f32
{
    __shared__ float fl[16 * 256];
    const int tid = threadIdx.x;
    const int m0  = blockIdx.x * 16;

    for (int e = tid; e < 4096; e += 256)
        fl[e] = f01[m0 * 256 + e];
    __syncthreads();

    const int o = tid;
    float acc[16];
    #pragma unroll
    for (int j = 0; j < 16; ++j) acc[j] = 0.0f;

    const v4f* wrow = (const v4f*)(out_w + (size_t)o * 256);
    for (int kk = 0; kk < 64; ++kk) {
        const v4f w = wrow[kk];
        #pragma unroll
        for (int j = 0; j < 16; ++j) {
            const v4f f = *(const v4f*)&fl[j * 256 + kk * 4];
            float a = acc[j];
            a = fmaf(f[0], w[0], a);
            a = fmaf(f[1], w[1], a);
            a = fmaf(f[2], w[2], a);
            a = fmaf(f[3], w[3], a);
            acc[j] = a;
        }
    }

    const float og = out_g[o] * BN_SCALE;
    const float ob = out_b[o];
    #pragma unroll
    for (int j = 0; j < 16; ++j) {
        float y = fmaf(acc[j], og, ob);
        y = fmaxf(y, 0.0f);
        out[(size_t)(m0 + j) * 256 + o] = y;
    }
}

// ---------------------------------------------------------------------------
extern "C" void kernel_launch(void* const* d_in, const int* in_sizes, int n_in,
                              void* d_out, int out_size, void* d_ws, size_t ws_size,
                              hipStream_t stream)
{
    const float* src_xyz   = (const float*)d_in[0];
    const float* src_feats = (const float*)d_in[1];
    const float* dst_xyz   = (const float*)d_in[2];
    const int*   idx0      = (const int*)d_in[3];
    const int*   idx1      = (const int*)d_in[4];
    const int*   empty0    = (const int*)d_in[5];
    const int*   empty1    = (const int*)d_in[6];
    const float* fc0_w     = (const float*)d_in[7];
    const float* fc0_b     = (const float*)d_in[8];
    const float* p0_w      = (const float*)d_in[9];
    const float* p0_g      = (const float*)d_in[10];
    const float* p0_b      = (const float*)d_in[11];
    const float* m0_w      = (const float*)d_in[12];
    const float* m0_g      = (const float*)d_in[13];
    const float* m0_b      = (const float*)d_in[14];
    const float* fc1_w     = (const float*)d_in[15];
    const float* fc1_b     = (const float*)d_in[16];
    const float* p1_w      = (const float*)d_in[17];
    const float* p1_g      = (const float*)d_in[18];
    const float* p1_b      = (const float*)d_in[19];
    const float* m1_w      = (const float*)d_in[20];
    const float* m1_g      = (const float*)d_in[21];
    const float* m1_b      = (const float*)d_in[22];
    const float* out_w     = (const float*)d_in[23];
    const float* out_g     = (const float*)d_in[24];
    const float* out_b     = (const float*)d_in[25];

    const int N = in_sizes[0] / 3;   // 65536
    const int M = in_sizes[2] / 3;   // 16384

    // workspace layout: cur0 (N*64 bf16) | cur1 (N*64 bf16) | f01 (M*256 f32)
    ushort_t* cur0 = (ushort_t*)d_ws;
    ushort_t* cur1 = cur0 + (size_t)N * 64;
    float*    f01  = (float*)((char*)d_ws + (size_t)2 * N * 64 * sizeof(ushort_t));

    cur_kernel<<<N / 32, 256, 0, stream>>>(src_feats, fc0_w, fc0_b, fc1_w, fc1_b,
                                           cur0, cur1);
    sa_kernel<16><<<M / 16, 256, 0, stream>>>(src_xyz, dst_xyz, idx0, empty0,
                                              p0_w, p0_g, p0_b, m0_w, m0_g, m0_b,
                                              cur0, f01, 0);
    sa_kernel<32><<<M / 16, 256, 0, stream>>>(src_xyz, dst_xyz, idx1, empty1,
                                              p1_w, p1_g, p1_b, m1_w, m1_g, m1_b,
                                              cur1, f01, 128);
    out_kernel<<<M / 16, 256, 0, stream>>>(f01, out_w, out_g, out_b,
                                           (float*)d_out);
}

// Round 3
// 238.814 us; speedup vs baseline: 1.3329x; 1.3329x over previous
//
#include <hip/hip_runtime.h>

typedef unsigned short ushort_t;
typedef unsigned int uint_t;
typedef __attribute__((ext_vector_type(8))) short v8s;   // 8 x bf16 (4 VGPRs)
typedef __attribute__((ext_vector_type(4))) float v4f;   // MFMA accumulator / float4

#define BN_SCALE 0.9999950000374997f

__device__ __forceinline__ float bf2f(ushort_t u) {
    union { uint_t i; float f; } v;
    v.i = ((uint_t)u) << 16;
    return v.f;
}
__device__ __forceinline__ ushort_t f2bf(float f) {
    union { uint_t i; float f; } v;
    v.f = f;
    uint_t b = v.i;
    b += 0x7fffu + ((b >> 16) & 1u);   // RNE
    return (ushort_t)(b >> 16);
}

__device__ __forceinline__ v8s cvt8(const float* __restrict__ p) {
    v8s f;
    #pragma unroll
    for (int j = 0; j < 8; ++j) f[j] = (short)f2bf(p[j]);
    return f;
}

// ---------------------------------------------------------------------------
// Kernel 0: convert out_w (256x256 f32) -> bf16 in workspace.
// ---------------------------------------------------------------------------
__global__ __launch_bounds__(256) void convw_kernel(
    const float* __restrict__ w, ushort_t* __restrict__ wb)
{
    const int i = (blockIdx.x * 256 + threadIdx.x) * 4;
    const v4f v = *(const v4f*)(w + i);
    ushort_t r0 = f2bf(v[0]), r1 = f2bf(v[1]), r2 = f2bf(v[2]), r3 = f2bf(v[3]);
    uint_t lo = (uint_t)r0 | ((uint_t)r1 << 16);
    uint_t hi = (uint_t)r2 | ((uint_t)r3 << 16);
    *(uint2*)(wb + i) = make_uint2(lo, hi);
}

// ---------------------------------------------------------------------------
// Kernel 1: cur{0,1}[n][d] = src_feats[n] . fc{0,1}_w[d] + fc{0,1}_b[d]
// Pure-MFMA GEMM: 64 rows/block (4 waves x 16 rows), 128 output cols
// (cur0's 64 | cur1's 64), K=64. No LDS. Bias folded into acc init.
// A[m=lane&15][k=quad*8+j], B[k][n]: lane n=lane&15 reads w-row contiguous.
// ---------------------------------------------------------------------------
__global__ __launch_bounds__(256) void cur_kernel(
    const float* __restrict__ src_feats,                     // (N,64) f32
    const float* __restrict__ fc0_w, const float* __restrict__ fc0_b,
    const float* __restrict__ fc1_w, const float* __restrict__ fc1_b,
    ushort_t* __restrict__ cur0, ushort_t* __restrict__ cur1)
{
    const int tid  = threadIdx.x;
    const int lane = tid & 63;
    const int wid  = tid >> 6;
    const int col  = lane & 15;
    const int quad = lane >> 4;
    const int row0 = blockIdx.x * 64 + wid * 16;

    v8s afrag[2];
    #pragma unroll
    for (int kf = 0; kf < 2; ++kf)
        afrag[kf] = cvt8(src_feats + (size_t)(row0 + col) * 64 + kf * 32 + quad * 8);

    v4f acc[8];
    v8s bfrag[8][2];
    #pragma unroll
    for (int ct = 0; ct < 8; ++ct) {
        const int d = (ct & 3) * 16 + col;
        const float* w = (ct < 4 ? fc0_w : fc1_w) + d * 64;
        const float  b = (ct < 4 ? fc0_b : fc1_b)[d];
        acc[ct] = (v4f){b, b, b, b};
        #pragma unroll
        for (int kf = 0; kf < 2; ++kf)
            bfrag[ct][kf] = cvt8(w + kf * 32 + quad * 8);
    }

    #pragma unroll
    for (int kf = 0; kf < 2; ++kf)
        #pragma unroll
        for (int ct = 0; ct < 8; ++ct)
            acc[ct] = __builtin_amdgcn_mfma_f32_16x16x32_bf16(
                afrag[kf], bfrag[ct][kf], acc[ct], 0, 0, 0);

    #pragma unroll
    for (int ct = 0; ct < 8; ++ct) {
        ushort_t* dst = (ct < 4) ? cur0 : cur1;
        const int d = (ct & 3) * 16 + col;
        #pragma unroll
        for (int r = 0; r < 4; ++r) {
            const int n = row0 + quad * 4 + r;
            dst[(size_t)n * 64 + d] = f2bf(acc[ct][r]);
        }
    }
}

// ---------------------------------------------------------------------------
// Kernel 2/3: SA layer. 16 dst points per block, 256 threads (4 waves).
// Phase A: x[s][d] = silu(bn(p_w . feat6)) + cur[idx[s]][d], masked -> LDS bf16
// Phase B: (S x 64) @ (64 x 128) via mfma_f32_16x16x32_bf16, bn+relu+max_s.
// f01 written as bf16 (consumed by MFMA out_kernel, which rounds anyway).
// ---------------------------------------------------------------------------
template <int S>
__global__ __launch_bounds__(256) void sa_kernel(
    const float* __restrict__ src_xyz,   // (N,3) f32
    const float* __restrict__ dst_xyz,   // (M,3) f32
    const int*   __restrict__ idx,       // (M,S)
    const int*   __restrict__ empty,     // (M,)
    const float* __restrict__ p_w,       // (64,6)
    const float* __restrict__ p_g,
    const float* __restrict__ p_b,
    const float* __restrict__ m_w,       // (128,64)
    const float* __restrict__ m_g,
    const float* __restrict__ m_b,
    const ushort_t* __restrict__ cur,    // (N,64) bf16
    ushort_t*    __restrict__ f01,       // (M,256) bf16
    int layer_off)
{
    constexpr int MPB = 16;
    constexpr int XP  = 72;              // padded row stride (ushorts)
    __shared__ ushort_t xlds[S * XP];

    const int tid  = threadIdx.x;
    const int lane = tid & 63;
    const int wid  = tid >> 6;           // 0..3
    const int m0   = blockIdx.x * MPB;

    // ---- phase-A per-thread constants (d = lane) ----
    const int d = lane;
    float pw[6];
    #pragma unroll
    for (int c = 0; c < 6; ++c) pw[c] = p_w[d * 6 + c];
    const float pg = p_g[d] * BN_SCALE;
    const float pb = p_b[d];

    // ---- phase-B per-wave constants ----
    const int col  = lane & 15;
    const int quad = lane >> 4;
    v8s bfrag[2][2];                     // [ct][kf]
    float mgv[2], mbv[2];
    #pragma unroll
    for (int c = 0; c < 2; ++c) {
        const int h = (wid * 2 + c) * 16 + col;
        #pragma unroll
        for (int kf = 0; kf < 2; ++kf)
            bfrag[c][kf] = cvt8(m_w + h * 64 + kf * 32 + quad * 8);
        mgv[c] = m_g[h] * BN_SCALE;
        mbv[c] = m_b[h];
    }

    for (int mi = 0; mi < MPB; ++mi) {
        const int m = m0 + mi;
        // ================= phase A =================
        const int   em  = empty[m];
        const float dpx = dst_xyz[m * 3 + 0];
        const float dpy = dst_xyz[m * 3 + 1];
        const float dpz = dst_xyz[m * 3 + 2];
        #pragma unroll
        for (int t = 0; t < S / 4; ++t) {
            const int s = wid + 4 * t;                 // wave-uniform s
            const int i = idx[m * S + s];
            const float f0 = src_xyz[i * 3 + 0] - dpx;
            const float f1 = src_xyz[i * 3 + 1] - dpy;
            const float f2 = src_xyz[i * 3 + 2] - dpz;
            float off = fmaf(pw[0], f0,
                        fmaf(pw[1], f1,
                        fmaf(pw[2], f2,
                        fmaf(pw[3], dpx,
                        fmaf(pw[4], dpy, pw[5] * dpz)))));
            const float v   = fmaf(off, pg, pb);
            const float sil = v / (1.0f + __expf(-v));
            float x = sil + bf2f(cur[i * 64 + d]);
            x = em ? 0.0f : x;
            xlds[s * XP + d] = f2bf(x);
        }
        __syncthreads();

        // ================= phase B =================
        v4f acc[S / 16][2];
        #pragma unroll
        for (int rt = 0; rt < S / 16; ++rt)
            #pragma unroll
            for (int c = 0; c < 2; ++c)
                acc[rt][c] = (v4f)0.0f;

        #pragma unroll
        for (int rt = 0; rt < S / 16; ++rt) {
            #pragma unroll
            for (int kf = 0; kf < 2; ++kf) {
                const v8s afrag =
                    *(const v8s*)(xlds + (rt * 16 + col) * XP + kf * 32 + quad * 8);
                acc[rt][0] = __builtin_amdgcn_mfma_f32_16x16x32_bf16(
                    afrag, bfrag[0][kf], acc[rt][0], 0, 0, 0);
                acc[rt][1] = __builtin_amdgcn_mfma_f32_16x16x32_bf16(
                    afrag, bfrag[1][kf], acc[rt][1], 0, 0, 0);
            }
        }

        // epilogue: bn, relu, max over s (C/D layout: col=lane&15, row=quad*4+r)
        float vmax0 = 0.0f, vmax1 = 0.0f;
        #pragma unroll
        for (int c = 0; c < 2; ++c) {
            float vm = 0.0f;   // relu(y)>=0, so 0 is a valid identity
            #pragma unroll
            for (int rt = 0; rt < S / 16; ++rt)
                #pragma unroll
                for (int r = 0; r < 4; ++r) {
                    const float y = fmaf(acc[rt][c][r], mgv[c], mbv[c]);
                    vm = fmaxf(vm, y);
                }
            vm = fmaxf(vm, __shfl_xor(vm, 16));
            vm = fmaxf(vm, __shfl_xor(vm, 32));
            if (c == 0) vmax0 = vm; else vmax1 = vm;
        }
        if (lane < 32) {
            const int c = lane >> 4;
            const float val = (c == 0) ? vmax0 : vmax1;
            f01[m * 256 + layer_off + (wid * 2 + c) * 16 + (lane & 15)] = f2bf(val);
        }
        __syncthreads();   // protect xlds before next m overwrites it
    }
}

// ---------------------------------------------------------------------------
// Kernel 4: out[m][o] = relu(bn(f01[m] . out_w[o])) via MFMA.
// 16 rows/block, 4 waves split the 256 output cols (4 col-tiles each), K=256.
// A-frags direct v8s loads from bf16 f01; B-frags from pre-converted out_wb.
// ---------------------------------------------------------------------------
__global__ __launch_bounds__(256) void out_kernel(
    const ushort_t* __restrict__ f01,     // (M,256) bf16
    const ushort_t* __restrict__ out_wb,  // (256,256) bf16
    const float*    __restrict__ out_g,
    const float*    __restrict__ out_b,
    float*          __restrict__ out)     // (M,256) f32
{
    const int tid  = threadIdx.x;
    const int lane = tid & 63;
    const int wid  = tid >> 6;
    const int col  = lane & 15;
    const int quad = lane >> 4;
    const int m0   = blockIdx.x * 16;

    v8s afrag[8];
    #pragma unroll
    for (int kf = 0; kf < 8; ++kf)
        afrag[kf] = *(const v8s*)(f01 + (size_t)(m0 + col) * 256 + kf * 32 + quad * 8);

    v4f acc[4];
    #pragma unroll
    for (int c = 0; c < 4; ++c) acc[c] = (v4f)0.0f;

    #pragma unroll
    for (int kf = 0; kf < 8; ++kf) {
        #pragma unroll
        for (int c = 0; c < 4; ++c) {
            const int n = (wid * 4 + c) * 16 + col;
            const v8s b = *(const v8s*)(out_wb + (size_t)n * 256 + kf * 32 + quad * 8);
            acc[c] = __builtin_amdgcn_mfma_f32_16x16x32_bf16(afrag[kf], b, acc[c], 0, 0, 0);
        }
    }

    #pragma unroll
    for (int c = 0; c < 4; ++c) {
        const int n  = (wid * 4 + c) * 16 + col;
        const float og = out_g[n] * BN_SCALE;
        const float ob = out_b[n];
        #pragma unroll
        for (int r = 0; r < 4; ++r) {
            float y = fmaf(acc[c][r], og, ob);
            y = fmaxf(y, 0.0f);
            out[(size_t)(m0 + quad * 4 + r) * 256 + n] = y;
        }
    }
}

// ---------------------------------------------------------------------------
extern "C" void kernel_launch(void* const* d_in, const int* in_sizes, int n_in,
                              void* d_out, int out_size, void* d_ws, size_t ws_size,
                              hipStream_t stream)
{
    const float* src_xyz   = (const float*)d_in[0];
    const float* src_feats = (const float*)d_in[1];
    const float* dst_xyz   = (const float*)d_in[2];
    const int*   idx0      = (const int*)d_in[3];
    const int*   idx1      = (const int*)d_in[4];
    const int*   empty0    = (const int*)d_in[5];
    const int*   empty1    = (const int*)d_in[6];
    const float* fc0_w     = (const float*)d_in[7];
    const float* fc0_b     = (const float*)d_in[8];
    const float* p0_w      = (const float*)d_in[9];
    const float* p0_g      = (const float*)d_in[10];
    const float* p0_b      = (const float*)d_in[11];
    const float* m0_w      = (const float*)d_in[12];
    const float* m0_g      = (const float*)d_in[13];
    const float* m0_b      = (const float*)d_in[14];
    const float* fc1_w     = (const float*)d_in[15];
    const float* fc1_b     = (const float*)d_in[16];
    const float* p1_w      = (const float*)d_in[17];
    const float* p1_g      = (const float*)d_in[18];
    const float* p1_b      = (const float*)d_in[19];
    const float* m1_w      = (const float*)d_in[20];
    const float* m1_g      = (const float*)d_in[21];
    const float* m1_b      = (const float*)d_in[22];
    const float* out_w     = (const float*)d_in[23];
    const float* out_g     = (const float*)d_in[24];
    const float* out_b     = (const float*)d_in[25];

    const int N = in_sizes[0] / 3;   // 65536
    const int M = in_sizes[2] / 3;   // 16384

    // ws layout: cur0 | cur1 (N*64 bf16 each) | f01 (M*256 bf16) | out_wb (256*256 bf16)
    ushort_t* cur0   = (ushort_t*)d_ws;
    ushort_t* cur1   = cur0 + (size_t)N * 64;
    ushort_t* f01    = cur1 + (size_t)N * 64;
    ushort_t* out_wb = f01 + (size_t)M * 256;

    convw_kernel<<<64, 256, 0, stream>>>(out_w, out_wb);
    cur_kernel<<<N / 64, 256, 0, stream>>>(src_feats, fc0_w, fc0_b, fc1_w, fc1_b,
                                           cur0, cur1);
    sa_kernel<16><<<M / 16, 256, 0, stream>>>(src_xyz, dst_xyz, idx0, empty0,
                                              p0_w, p0_g, p0_b, m0_w, m0_g, m0_b,
                                              cur0, f01, 0);
    sa_kernel<32><<<M / 16, 256, 0, stream>>>(src_xyz, dst_xyz, idx1, empty1,
                                              p1_w, p1_g, p1_b, m1_w, m1_g, m1_b,
                                              cur1, f01, 128);
    out_kernel<<<M / 16, 256, 0, stream>>>(f01, out_wb, out_g, out_b,
                                           (float*)d_out);
}

// Round 4
// 225.158 us; speedup vs baseline: 1.4138x; 1.0606x over previous
//
#include <hip/hip_runtime.h>

typedef unsigned short ushort_t;
typedef unsigned int uint_t;
typedef __attribute__((ext_vector_type(8))) short v8s;   // 8 x bf16 (4 VGPRs)
typedef __attribute__((ext_vector_type(4))) float v4f;   // MFMA accumulator / float4

#define BN_SCALE 0.9999950000374997f

__device__ __forceinline__ float bf2f(ushort_t u) {
    union { uint_t i; float f; } v;
    v.i = ((uint_t)u) << 16;
    return v.f;
}
__device__ __forceinline__ ushort_t f2bf(float f) {
    union { uint_t i; float f; } v;
    v.f = f;
    uint_t b = v.i;
    b += 0x7fffu + ((b >> 16) & 1u);   // RNE
    return (ushort_t)(b >> 16);
}

__device__ __forceinline__ v8s cvt8(const float* __restrict__ p) {
    v8s f;
    #pragma unroll
    for (int j = 0; j < 8; ++j) f[j] = (short)f2bf(p[j]);
    return f;
}

// ---------------------------------------------------------------------------
// Kernel 0: convert out_w (256x256 f32) -> bf16 in workspace.
// ---------------------------------------------------------------------------
__global__ __launch_bounds__(256) void convw_kernel(
    const float* __restrict__ w, ushort_t* __restrict__ wb)
{
    const int i = (blockIdx.x * 256 + threadIdx.x) * 4;
    const v4f v = *(const v4f*)(w + i);
    ushort_t r0 = f2bf(v[0]), r1 = f2bf(v[1]), r2 = f2bf(v[2]), r3 = f2bf(v[3]);
    uint_t lo = (uint_t)r0 | ((uint_t)r1 << 16);
    uint_t hi = (uint_t)r2 | ((uint_t)r3 << 16);
    *(uint2*)(wb + i) = make_uint2(lo, hi);
}

// ---------------------------------------------------------------------------
// Kernel 1: cur{0,1}[n][d] = src_feats[n] . fc{0,1}_w[d] + fc{0,1}_b[d]
// Pure-MFMA GEMM, no LDS, bias folded into acc init. 64 rows/block.
// ---------------------------------------------------------------------------
__global__ __launch_bounds__(256) void cur_kernel(
    const float* __restrict__ src_feats,                     // (N,64) f32
    const float* __restrict__ fc0_w, const float* __restrict__ fc0_b,
    const float* __restrict__ fc1_w, const float* __restrict__ fc1_b,
    ushort_t* __restrict__ cur0, ushort_t* __restrict__ cur1)
{
    const int tid  = threadIdx.x;
    const int lane = tid & 63;
    const int wid  = tid >> 6;
    const int col  = lane & 15;
    const int quad = lane >> 4;
    const int row0 = blockIdx.x * 64 + wid * 16;

    v8s afrag[2];
    #pragma unroll
    for (int kf = 0; kf < 2; ++kf)
        afrag[kf] = cvt8(src_feats + (size_t)(row0 + col) * 64 + kf * 32 + quad * 8);

    v4f acc[8];
    v8s bfrag[8][2];
    #pragma unroll
    for (int ct = 0; ct < 8; ++ct) {
        const int d = (ct & 3) * 16 + col;
        const float* w = (ct < 4 ? fc0_w : fc1_w) + d * 64;
        const float  b = (ct < 4 ? fc0_b : fc1_b)[d];
        acc[ct] = (v4f){b, b, b, b};
        #pragma unroll
        for (int kf = 0; kf < 2; ++kf)
            bfrag[ct][kf] = cvt8(w + kf * 32 + quad * 8);
    }

    #pragma unroll
    for (int kf = 0; kf < 2; ++kf)
        #pragma unroll
        for (int ct = 0; ct < 8; ++ct)
            acc[ct] = __builtin_amdgcn_mfma_f32_16x16x32_bf16(
                afrag[kf], bfrag[ct][kf], acc[ct], 0, 0, 0);

    #pragma unroll
    for (int ct = 0; ct < 8; ++ct) {
        ushort_t* dst = (ct < 4) ? cur0 : cur1;
        const int d = (ct & 3) * 16 + col;
        #pragma unroll
        for (int r = 0; r < 4; ++r) {
            const int n = row0 + quad * 4 + r;
            dst[(size_t)n * 64 + d] = f2bf(acc[ct][r]);
        }
    }
}

// ---------------------------------------------------------------------------
// Kernel 2/3: SA layer. 8 dst points per block, 256 threads (4 waves).
// Phase A (all waves cooperatively): x[mi][s][d] -> LDS bf16, ONE barrier.
// Phase B (per wave, col-split, 8 independent m's): MFMA + bn/relu/max_s.
// ---------------------------------------------------------------------------
template <int S>
__global__ __launch_bounds__(256) void sa_kernel(
    const float* __restrict__ src_xyz,   // (N,3) f32
    const float* __restrict__ dst_xyz,   // (M,3) f32
    const int*   __restrict__ idx,       // (M,S)
    const int*   __restrict__ empty,     // (M,)
    const float* __restrict__ p_w,       // (64,6)
    const float* __restrict__ p_g,
    const float* __restrict__ p_b,
    const float* __restrict__ m_w,       // (128,64)
    const float* __restrict__ m_g,
    const float* __restrict__ m_b,
    const ushort_t* __restrict__ cur,    // (N,64) bf16
    ushort_t*    __restrict__ f01,       // (M,256) bf16
    int layer_off)
{
    constexpr int MB = 8;                // m's per block
    constexpr int XP = 72;               // padded row stride (ushorts), 144 B
    __shared__ ushort_t xlds[MB * S * XP];

    const int tid  = threadIdx.x;
    const int lane = tid & 63;
    const int wid  = tid >> 6;           // 0..3
    const int m0   = blockIdx.x * MB;

    // ---- phase-A per-thread constants (d = lane) ----
    const int d = lane;
    float pw[6];
    #pragma unroll
    for (int c = 0; c < 6; ++c) pw[c] = p_w[d * 6 + c];
    const float pg = p_g[d] * BN_SCALE;
    const float pb = p_b[d];

    // ---- phase-B per-wave constants ----
    const int col  = lane & 15;
    const int quad = lane >> 4;
    v8s bfrag[2][2];                     // [ct][kf]
    float mgv[2], mbv[2];
    #pragma unroll
    for (int c = 0; c < 2; ++c) {
        const int h = (wid * 2 + c) * 16 + col;
        #pragma unroll
        for (int kf = 0; kf < 2; ++kf)
            bfrag[c][kf] = cvt8(m_w + h * 64 + kf * 32 + quad * 8);
        mgv[c] = m_g[h] * BN_SCALE;
        mbv[c] = m_b[h];
    }

    // ================= phase A: fill all MB m's, one barrier =================
    #pragma unroll
    for (int mi = 0; mi < MB; ++mi) {
        const int m = m0 + mi;
        const int   em  = empty[m];
        const float dpx = dst_xyz[m * 3 + 0];
        const float dpy = dst_xyz[m * 3 + 1];
        const float dpz = dst_xyz[m * 3 + 2];
        #pragma unroll
        for (int tt = 0; tt < S / 4; ++tt) {
            const int s = wid + 4 * tt;               // wave-uniform s
            const int i = idx[m * S + s];
            const float f0 = src_xyz[i * 3 + 0] - dpx;
            const float f1 = src_xyz[i * 3 + 1] - dpy;
            const float f2 = src_xyz[i * 3 + 2] - dpz;
            float off = fmaf(pw[0], f0,
                        fmaf(pw[1], f1,
                        fmaf(pw[2], f2,
                        fmaf(pw[3], dpx,
                        fmaf(pw[4], dpy, pw[5] * dpz)))));
            const float v   = fmaf(off, pg, pb);
            const float sil = v * __builtin_amdgcn_rcpf(1.0f + __expf(-v));
            float x = sil + bf2f(cur[i * 64 + d]);
            x = em ? 0.0f : x;
            xlds[(mi * S + s) * XP + d] = f2bf(x);
        }
    }
    __syncthreads();

    // ================= phase B: 8 independent m's per wave =================
    #pragma unroll
    for (int mi = 0; mi < MB; ++mi) {
        const int m = m0 + mi;
        v4f acc[S / 16][2];
        #pragma unroll
        for (int rt = 0; rt < S / 16; ++rt)
            #pragma unroll
            for (int c = 0; c < 2; ++c)
                acc[rt][c] = (v4f)0.0f;

        #pragma unroll
        for (int rt = 0; rt < S / 16; ++rt) {
            #pragma unroll
            for (int kf = 0; kf < 2; ++kf) {
                const v8s afrag = *(const v8s*)(
                    xlds + ((mi * S + rt * 16 + col)) * XP + kf * 32 + quad * 8);
                acc[rt][0] = __builtin_amdgcn_mfma_f32_16x16x32_bf16(
                    afrag, bfrag[0][kf], acc[rt][0], 0, 0, 0);
                acc[rt][1] = __builtin_amdgcn_mfma_f32_16x16x32_bf16(
                    afrag, bfrag[1][kf], acc[rt][1], 0, 0, 0);
            }
        }

        // epilogue: bn, relu, max over s (C/D layout: col=lane&15, row=quad*4+r)
        float vmax0 = 0.0f, vmax1 = 0.0f;
        #pragma unroll
        for (int c = 0; c < 2; ++c) {
            float vm = 0.0f;   // relu(y)>=0, so 0 is a valid identity
            #pragma unroll
            for (int rt = 0; rt < S / 16; ++rt)
                #pragma unroll
                for (int r = 0; r < 4; ++r) {
                    const float y = fmaf(acc[rt][c][r], mgv[c], mbv[c]);
                    vm = fmaxf(vm, y);
                }
            vm = fmaxf(vm, __shfl_xor(vm, 16));
            vm = fmaxf(vm, __shfl_xor(vm, 32));
            if (c == 0) vmax0 = vm; else vmax1 = vm;
        }
        if (lane < 32) {
            const int c = lane >> 4;
            const float val = (c == 0) ? vmax0 : vmax1;
            f01[m * 256 + layer_off + (wid * 2 + c) * 16 + (lane & 15)] = f2bf(val);
        }
    }
}

// ---------------------------------------------------------------------------
// Kernel 4: out[m][o] = relu(bn(f01[m] . out_w[o])) via MFMA.
// 16 rows/block, 4 waves split the 256 output cols, K=256.
// ---------------------------------------------------------------------------
__global__ __launch_bounds__(256) void out_kernel(
    const ushort_t* __restrict__ f01,     // (M,256) bf16
    const ushort_t* __restrict__ out_wb,  // (256,256) bf16
    const float*    __restrict__ out_g,
    const float*    __restrict__ out_b,
    float*          __restrict__ out)     // (M,256) f32
{
    const int tid  = threadIdx.x;
    const int lane = tid & 63;
    const int wid  = tid >> 6;
    const int col  = lane & 15;
    const int quad = lane >> 4;
    const int m0   = blockIdx.x * 16;

    v8s afrag[8];
    #pragma unroll
    for (int kf = 0; kf < 8; ++kf)
        afrag[kf] = *(const v8s*)(f01 + (size_t)(m0 + col) * 256 + kf * 32 + quad * 8);

    v4f acc[4];
    #pragma unroll
    for (int c = 0; c < 4; ++c) acc[c] = (v4f)0.0f;

    #pragma unroll
    for (int kf = 0; kf < 8; ++kf) {
        #pragma unroll
        for (int c = 0; c < 4; ++c) {
            const int n = (wid * 4 + c) * 16 + col;
            const v8s b = *(const v8s*)(out_wb + (size_t)n * 256 + kf * 32 + quad * 8);
            acc[c] = __builtin_amdgcn_mfma_f32_16x16x32_bf16(afrag[kf], b, acc[c], 0, 0, 0);
        }
    }

    #pragma unroll
    for (int c = 0; c < 4; ++c) {
        const int n  = (wid * 4 + c) * 16 + col;
        const float og = out_g[n] * BN_SCALE;
        const float ob = out_b[n];
        #pragma unroll
        for (int r = 0; r < 4; ++r) {
            float y = fmaf(acc[c][r], og, ob);
            y = fmaxf(y, 0.0f);
            out[(size_t)(m0 + quad * 4 + r) * 256 + n] = y;
        }
    }
}

// ---------------------------------------------------------------------------
extern "C" void kernel_launch(void* const* d_in, const int* in_sizes, int n_in,
                              void* d_out, int out_size, void* d_ws, size_t ws_size,
                              hipStream_t stream)
{
    const float* src_xyz   = (const float*)d_in[0];
    const float* src_feats = (const float*)d_in[1];
    const float* dst_xyz   = (const float*)d_in[2];
    const int*   idx0      = (const int*)d_in[3];
    const int*   idx1      = (const int*)d_in[4];
    const int*   empty0    = (const int*)d_in[5];
    const int*   empty1    = (const int*)d_in[6];
    const float* fc0_w     = (const float*)d_in[7];
    const float* fc0_b     = (const float*)d_in[8];
    const float* p0_w      = (const float*)d_in[9];
    const float* p0_g      = (const float*)d_in[10];
    const float* p0_b      = (const float*)d_in[11];
    const float* m0_w      = (const float*)d_in[12];
    const float* m0_g      = (const float*)d_in[13];
    const float* m0_b      = (const float*)d_in[14];
    const float* fc1_w     = (const float*)d_in[15];
    const float* fc1_b     = (const float*)d_in[16];
    const float* p1_w      = (const float*)d_in[17];
    const float* p1_g      = (const float*)d_in[18];
    const float* p1_b      = (const float*)d_in[19];
    const float* m1_w      = (const float*)d_in[20];
    const float* m1_g      = (const float*)d_in[21];
    const float* m1_b      = (const float*)d_in[22];
    const float* out_w     = (const float*)d_in[23];
    const float* out_g     = (const float*)d_in[24];
    const float* out_b     = (const float*)d_in[25];

    const int N = in_sizes[0] / 3;   // 65536
    const int M = in_sizes[2] / 3;   // 16384

    // ws layout: cur0 | cur1 (N*64 bf16 each) | f01 (M*256 bf16) | out_wb (256*256 bf16)
    ushort_t* cur0   = (ushort_t*)d_ws;
    ushort_t* cur1   = cur0 + (size_t)N * 64;
    ushort_t* f01    = cur1 + (size_t)N * 64;
    ushort_t* out_wb = f01 + (size_t)M * 256;

    convw_kernel<<<64, 256, 0, stream>>>(out_w, out_wb);
    cur_kernel<<<N / 64, 256, 0, stream>>>(src_feats, fc0_w, fc0_b, fc1_w, fc1_b,
                                           cur0, cur1);
    sa_kernel<16><<<M / 8, 256, 0, stream>>>(src_xyz, dst_xyz, idx0, empty0,
                                             p0_w, p0_g, p0_b, m0_w, m0_g, m0_b,
                                             cur0, f01, 0);
    sa_kernel<32><<<M / 8, 256, 0, stream>>>(src_xyz, dst_xyz, idx1, empty1,
                                             p1_w, p1_g, p1_b, m1_w, m1_g, m1_b,
                                             cur1, f01, 128);
    out_kernel<<<M / 16, 256, 0, stream>>>(f01, out_wb, out_g, out_b,
                                           (float*)d_out);
}

// Round 5
// 213.933 us; speedup vs baseline: 1.4879x; 1.0525x over previous
//
#include <hip/hip_runtime.h>

typedef unsigned short ushort_t;
typedef unsigned int uint_t;
typedef __attribute__((ext_vector_type(8))) short v8s;   // 8 x bf16 (4 VGPRs)
typedef __attribute__((ext_vector_type(4))) float v4f;   // MFMA accumulator / float4

#define BN_SCALE 0.9999950000374997f

__device__ __forceinline__ float bf2f(ushort_t u) {
    union { uint_t i; float f; } v;
    v.i = ((uint_t)u) << 16;
    return v.f;
}
__device__ __forceinline__ ushort_t f2bf(float f) {
    union { uint_t i; float f; } v;
    v.f = f;
    uint_t b = v.i;
    b += 0x7fffu + ((b >> 16) & 1u);   // RNE
    return (ushort_t)(b >> 16);
}

__device__ __forceinline__ v8s cvt8(const float* __restrict__ p) {
    v8s f;
    #pragma unroll
    for (int j = 0; j < 8; ++j) f[j] = (short)f2bf(p[j]);
    return f;
}

// ---------------------------------------------------------------------------
// Kernel 0: convert out_w (256x256 f32) -> bf16 in workspace.
// ---------------------------------------------------------------------------
__global__ __launch_bounds__(256) void convw_kernel(
    const float* __restrict__ w, ushort_t* __restrict__ wb)
{
    const int i = (blockIdx.x * 256 + threadIdx.x) * 4;
    const v4f v = *(const v4f*)(w + i);
    ushort_t r0 = f2bf(v[0]), r1 = f2bf(v[1]), r2 = f2bf(v[2]), r3 = f2bf(v[3]);
    uint_t lo = (uint_t)r0 | ((uint_t)r1 << 16);
    uint_t hi = (uint_t)r2 | ((uint_t)r3 << 16);
    *(uint2*)(wb + i) = make_uint2(lo, hi);
}

// ---------------------------------------------------------------------------
// Kernel 1: cur{0,1}[n][d] = src_feats[n] . fc{0,1}_w[d] + fc{0,1}_b[d]
// Pure-MFMA GEMM, no LDS, bias folded into acc init. 64 rows/block.
// ---------------------------------------------------------------------------
__global__ __launch_bounds__(256) void cur_kernel(
    const float* __restrict__ src_feats,                     // (N,64) f32
    const float* __restrict__ fc0_w, const float* __restrict__ fc0_b,
    const float* __restrict__ fc1_w, const float* __restrict__ fc1_b,
    ushort_t* __restrict__ cur0, ushort_t* __restrict__ cur1)
{
    const int tid  = threadIdx.x;
    const int lane = tid & 63;
    const int wid  = tid >> 6;
    const int col  = lane & 15;
    const int quad = lane >> 4;
    const int row0 = blockIdx.x * 64 + wid * 16;

    v8s afrag[2];
    #pragma unroll
    for (int kf = 0; kf < 2; ++kf)
        afrag[kf] = cvt8(src_feats + (size_t)(row0 + col) * 64 + kf * 32 + quad * 8);

    v4f acc[8];
    v8s bfrag[8][2];
    #pragma unroll
    for (int ct = 0; ct < 8; ++ct) {
        const int d = (ct & 3) * 16 + col;
        const float* w = (ct < 4 ? fc0_w : fc1_w) + d * 64;
        const float  b = (ct < 4 ? fc0_b : fc1_b)[d];
        acc[ct] = (v4f){b, b, b, b};
        #pragma unroll
        for (int kf = 0; kf < 2; ++kf)
            bfrag[ct][kf] = cvt8(w + kf * 32 + quad * 8);
    }

    #pragma unroll
    for (int kf = 0; kf < 2; ++kf)
        #pragma unroll
        for (int ct = 0; ct < 8; ++ct)
            acc[ct] = __builtin_amdgcn_mfma_f32_16x16x32_bf16(
                afrag[kf], bfrag[ct][kf], acc[ct], 0, 0, 0);

    #pragma unroll
    for (int ct = 0; ct < 8; ++ct) {
        ushort_t* dst = (ct < 4) ? cur0 : cur1;
        const int d = (ct & 3) * 16 + col;
        #pragma unroll
        for (int r = 0; r < 4; ++r) {
            const int n = row0 + quad * 4 + r;
            dst[(size_t)n * 64 + d] = f2bf(acc[ct][r]);
        }
    }
}

// ---------------------------------------------------------------------------
// Kernel 2/3: SA layer. 8 dst points per block, 256 threads (4 waves).
// Prologue: thread t gathers idx/xyz for (m,s) pair t -> relative coords in
//   LDS (coalesced idx load; all gather latency prepaid before one barrier).
// Phase A: per (m,s): broadcast LDS float4 read + 3-FMA dot (BN gain folded
//   into p_w, per-m vbase) + silu + coalesced cur gather -> x in LDS bf16.
// Phase B: per-wave col-split MFMA over 8 independent m's + bn/relu/max_s.
// ---------------------------------------------------------------------------
template <int S>
__global__ __launch_bounds__(256) void sa_kernel(
    const float* __restrict__ src_xyz,   // (N,3) f32
    const float* __restrict__ dst_xyz,   // (M,3) f32
    const int*   __restrict__ idx,       // (M,S)
    const int*   __restrict__ empty,     // (M,)
    const float* __restrict__ p_w,       // (64,6)
    const float* __restrict__ p_g,
    const float* __restrict__ p_b,
    const float* __restrict__ m_w,       // (128,64)
    const float* __restrict__ m_g,
    const float* __restrict__ m_b,
    const ushort_t* __restrict__ cur,    // (N,64) bf16
    ushort_t*    __restrict__ f01,       // (M,256) bf16
    int layer_off)
{
    constexpr int MB    = 8;             // m's per block
    constexpr int XP    = 72;            // padded row stride (ushorts), 144 B
    constexpr int PAIRS = MB * S;        // 128 (S=16) or 256 (S=32)
    __shared__ ushort_t xlds[MB * S * XP];
    __shared__ v4f      flds[PAIRS];     // (sp-dp).xyz, bitcast(i)

    const int tid  = threadIdx.x;
    const int lane = tid & 63;
    const int wid  = tid >> 6;           // 0..3
    const int m0   = blockIdx.x * MB;

    // ---- prologue: coalesced idx + xyz gathers -> flds ----
    if (S == 32 || tid < PAIRS) {
        const int mi = tid / S;
        const int m  = m0 + mi;
        const int i  = idx[(size_t)m * S + (tid & (S - 1))];
        const float dx = dst_xyz[m * 3 + 0];
        const float dy = dst_xyz[m * 3 + 1];
        const float dz = dst_xyz[m * 3 + 2];
        v4f r;
        r[0] = src_xyz[i * 3 + 0] - dx;
        r[1] = src_xyz[i * 3 + 1] - dy;
        r[2] = src_xyz[i * 3 + 2] - dz;
        r[3] = __int_as_float(i);
        flds[tid] = r;
    }

    // ---- per-lane d-constants (d = lane) ----
    const int d = lane;
    const float pg = p_g[d] * BN_SCALE;
    const float pb = p_b[d];
    const float pwg0 = p_w[d * 6 + 0] * pg;
    const float pwg1 = p_w[d * 6 + 1] * pg;
    const float pwg2 = p_w[d * 6 + 2] * pg;
    const float pd0  = p_w[d * 6 + 3] * pg;
    const float pd1  = p_w[d * 6 + 4] * pg;
    const float pd2  = p_w[d * 6 + 5] * pg;

    // ---- phase-B per-wave constants ----
    const int col  = lane & 15;
    const int quad = lane >> 4;
    v8s bfrag[2][2];                     // [ct][kf]
    float mgv[2], mbv[2];
    #pragma unroll
    for (int c = 0; c < 2; ++c) {
        const int h = (wid * 2 + c) * 16 + col;
        #pragma unroll
        for (int kf = 0; kf < 2; ++kf)
            bfrag[c][kf] = cvt8(m_w + h * 64 + kf * 32 + quad * 8);
        mgv[c] = m_g[h] * BN_SCALE;
        mbv[c] = m_b[h];
    }

    __syncthreads();

    // ================= phase A =================
    const ushort_t* cur_d = cur + d;     // per-lane base (i*64 + d)
    #pragma unroll
    for (int mi = 0; mi < MB; ++mi) {
        const int m = m0 + mi;
        const float dx = dst_xyz[m * 3 + 0];
        const float dy = dst_xyz[m * 3 + 1];
        const float dz = dst_xyz[m * 3 + 2];
        const float vbase = fmaf(pd0, dx, fmaf(pd1, dy, fmaf(pd2, dz, pb)));
        const int em = empty[m];
        #pragma unroll
        for (int tt = 0; tt < S / 4; ++tt) {
            const int s = wid * (S / 4) + tt;
            const v4f r = flds[mi * S + s];          // broadcast b128 read
            const int i = __float_as_int(r[3]);
            const float v = fmaf(pwg0, r[0], fmaf(pwg1, r[1], fmaf(pwg2, r[2], vbase)));
            const float e = __expf(-v);
            const float rc = __builtin_amdgcn_rcpf(1.0f + e);
            const float cf = bf2f(cur_d[(size_t)i * 64]);
            float x = fmaf(v, rc, cf);               // silu + cur in one fma
            x = em ? 0.0f : x;
            xlds[(mi * S + s) * XP + d] = f2bf(x);
        }
    }
    __syncthreads();

    // ================= phase B: 8 independent m's per wave =================
    #pragma unroll
    for (int mi = 0; mi < MB; ++mi) {
        const int m = m0 + mi;
        v4f acc[S / 16][2];
        #pragma unroll
        for (int rt = 0; rt < S / 16; ++rt)
            #pragma unroll
            for (int c = 0; c < 2; ++c)
                acc[rt][c] = (v4f)0.0f;

        #pragma unroll
        for (int rt = 0; rt < S / 16; ++rt) {
            #pragma unroll
            for (int kf = 0; kf < 2; ++kf) {
                const v8s afrag = *(const v8s*)(
                    xlds + ((mi * S + rt * 16 + col)) * XP + kf * 32 + quad * 8);
                acc[rt][0] = __builtin_amdgcn_mfma_f32_16x16x32_bf16(
                    afrag, bfrag[0][kf], acc[rt][0], 0, 0, 0);
                acc[rt][1] = __builtin_amdgcn_mfma_f32_16x16x32_bf16(
                    afrag, bfrag[1][kf], acc[rt][1], 0, 0, 0);
            }
        }

        // epilogue: bn, relu, max over s (C/D layout: col=lane&15, row=quad*4+r)
        float vmax0 = 0.0f, vmax1 = 0.0f;
        #pragma unroll
        for (int c = 0; c < 2; ++c) {
            float vm = 0.0f;   // relu(y)>=0, so 0 is a valid identity
            #pragma unroll
            for (int rt = 0; rt < S / 16; ++rt)
                #pragma unroll
                for (int r = 0; r < 4; ++r) {
                    const float y = fmaf(acc[rt][c][r], mgv[c], mbv[c]);
                    vm = fmaxf(vm, y);
                }
            vm = fmaxf(vm, __shfl_xor(vm, 16));
            vm = fmaxf(vm, __shfl_xor(vm, 32));
            if (c == 0) vmax0 = vm; else vmax1 = vm;
        }
        if (lane < 32) {
            const int c = lane >> 4;
            const float val = (c == 0) ? vmax0 : vmax1;
            f01[m * 256 + layer_off + (wid * 2 + c) * 16 + (lane & 15)] = f2bf(val);
        }
    }
}

// ---------------------------------------------------------------------------
// Kernel 4: out[m][o] = relu(bn(f01[m] . out_w[o])) via MFMA.
// 16 rows/block, 4 waves split the 256 output cols, K=256.
// ---------------------------------------------------------------------------
__global__ __launch_bounds__(256) void out_kernel(
    const ushort_t* __restrict__ f01,     // (M,256) bf16
    const ushort_t* __restrict__ out_wb,  // (256,256) bf16
    const float*    __restrict__ out_g,
    const float*    __restrict__ out_b,
    float*          __restrict__ out)     // (M,256) f32
{
    const int tid  = threadIdx.x;
    const int lane = tid & 63;
    const int wid  = tid >> 6;
    const int col  = lane & 15;
    const int quad = lane >> 4;
    const int m0   = blockIdx.x * 16;

    v8s afrag[8];
    #pragma unroll
    for (int kf = 0; kf < 8; ++kf)
        afrag[kf] = *(const v8s*)(f01 + (size_t)(m0 + col) * 256 + kf * 32 + quad * 8);

    v4f acc[4];
    #pragma unroll
    for (int c = 0; c < 4; ++c) acc[c] = (v4f)0.0f;

    #pragma unroll
    for (int kf = 0; kf < 8; ++kf) {
        #pragma unroll
        for (int c = 0; c < 4; ++c) {
            const int n = (wid * 4 + c) * 16 + col;
            const v8s b = *(const v8s*)(out_wb + (size_t)n * 256 + kf * 32 + quad * 8);
            acc[c] = __builtin_amdgcn_mfma_f32_16x16x32_bf16(afrag[kf], b, acc[c], 0, 0, 0);
        }
    }

    #pragma unroll
    for (int c = 0; c < 4; ++c) {
        const int n  = (wid * 4 + c) * 16 + col;
        const float og = out_g[n] * BN_SCALE;
        const float ob = out_b[n];
        #pragma unroll
        for (int r = 0; r < 4; ++r) {
            float y = fmaf(acc[c][r], og, ob);
            y = fmaxf(y, 0.0f);
            out[(size_t)(m0 + quad * 4 + r) * 256 + n] = y;
        }
    }
}

// ---------------------------------------------------------------------------
extern "C" void kernel_launch(void* const* d_in, const int* in_sizes, int n_in,
                              void* d_out, int out_size, void* d_ws, size_t ws_size,
                              hipStream_t stream)
{
    const float* src_xyz   = (const float*)d_in[0];
    const float* src_feats = (const float*)d_in[1];
    const float* dst_xyz   = (const float*)d_in[2];
    const int*   idx0      = (const int*)d_in[3];
    const int*   idx1      = (const int*)d_in[4];
    const int*   empty0    = (const int*)d_in[5];
    const int*   empty1    = (const int*)d_in[6];
    const float* fc0_w     = (const float*)d_in[7];
    const float* fc0_b     = (const float*)d_in[8];
    const float* p0_w      = (const float*)d_in[9];
    const float* p0_g      = (const float*)d_in[10];
    const float* p0_b      = (const float*)d_in[11];
    const float* m0_w      = (const float*)d_in[12];
    const float* m0_g      = (const float*)d_in[13];
    const float* m0_b      = (const float*)d_in[14];
    const float* fc1_w     = (const float*)d_in[15];
    const float* fc1_b     = (const float*)d_in[16];
    const float* p1_w      = (const float*)d_in[17];
    const float* p1_g      = (const float*)d_in[18];
    const float* p1_b      = (const float*)d_in[19];
    const float* m1_w      = (const float*)d_in[20];
    const float* m1_g      = (const float*)d_in[21];
    const float* m1_b      = (const float*)d_in[22];
    const float* out_w     = (const float*)d_in[23];
    const float* out_g     = (const float*)d_in[24];
    const float* out_b     = (const float*)d_in[25];

    const int N = in_sizes[0] / 3;   // 65536
    const int M = in_sizes[2] / 3;   // 16384

    // ws layout: cur0 | cur1 (N*64 bf16 each) | f01 (M*256 bf16) | out_wb (256*256 bf16)
    ushort_t* cur0   = (ushort_t*)d_ws;
    ushort_t* cur1   = cur0 + (size_t)N * 64;
    ushort_t* f01    = cur1 + (size_t)N * 64;
    ushort_t* out_wb = f01 + (size_t)M * 256;

    convw_kernel<<<64, 256, 0, stream>>>(out_w, out_wb);
    cur_kernel<<<N / 64, 256, 0, stream>>>(src_feats, fc0_w, fc0_b, fc1_w, fc1_b,
                                           cur0, cur1);
    sa_kernel<16><<<M / 8, 256, 0, stream>>>(src_xyz, dst_xyz, idx0, empty0,
                                             p0_w, p0_g, p0_b, m0_w, m0_g, m0_b,
                                             cur0, f01, 0);
    sa_kernel<32><<<M / 8, 256, 0, stream>>>(src_xyz, dst_xyz, idx1, empty1,
                                             p1_w, p1_g, p1_b, m1_w, m1_g, m1_b,
                                             cur1, f01, 128);
    out_kernel<<<M / 16, 256, 0, stream>>>(f01, out_wb, out_g, out_b,
                                           (float*)d_out);
}

// Round 6
// 210.004 us; speedup vs baseline: 1.5158x; 1.0187x over previous
//
#include <hip/hip_runtime.h>

typedef unsigned short ushort_t;
typedef unsigned int uint_t;
typedef __attribute__((ext_vector_type(8))) short v8s;   // 8 x bf16 (4 VGPRs)
typedef __attribute__((ext_vector_type(4))) float v4f;   // MFMA accumulator / float4

#define BN_SCALE 0.9999950000374997f

__device__ __forceinline__ float bf2f(ushort_t u) {
    union { uint_t i; float f; } v;
    v.i = ((uint_t)u) << 16;
    return v.f;
}
__device__ __forceinline__ ushort_t f2bf(float f) {
    union { uint_t i; float f; } v;
    v.f = f;
    uint_t b = v.i;
    b += 0x7fffu + ((b >> 16) & 1u);   // RNE
    return (ushort_t)(b >> 16);
}

__device__ __forceinline__ v8s cvt8(const float* __restrict__ p) {
    v8s f;
    #pragma unroll
    for (int j = 0; j < 8; ++j) f[j] = (short)f2bf(p[j]);
    return f;
}

// ---------------------------------------------------------------------------
// Kernel 0: convert out_w (256x256 f32) -> bf16 in workspace.
// ---------------------------------------------------------------------------
__global__ __launch_bounds__(256) void convw_kernel(
    const float* __restrict__ w, ushort_t* __restrict__ wb)
{
    const int i = (blockIdx.x * 256 + threadIdx.x) * 4;
    const v4f v = *(const v4f*)(w + i);
    ushort_t r0 = f2bf(v[0]), r1 = f2bf(v[1]), r2 = f2bf(v[2]), r3 = f2bf(v[3]);
    uint_t lo = (uint_t)r0 | ((uint_t)r1 << 16);
    uint_t hi = (uint_t)r2 | ((uint_t)r3 << 16);
    *(uint2*)(wb + i) = make_uint2(lo, hi);
}

// ---------------------------------------------------------------------------
// Kernel 1: cur{0,1}[n][d] = src_feats[n] . fc{0,1}_w[d] + fc{0,1}_b[d]
// Pure-MFMA GEMM, no LDS, bias folded into acc init. 64 rows/block.
// ---------------------------------------------------------------------------
__global__ __launch_bounds__(256) void cur_kernel(
    const float* __restrict__ src_feats,                     // (N,64) f32
    const float* __restrict__ fc0_w, const float* __restrict__ fc0_b,
    const float* __restrict__ fc1_w, const float* __restrict__ fc1_b,
    ushort_t* __restrict__ cur0, ushort_t* __restrict__ cur1)
{
    const int tid  = threadIdx.x;
    const int lane = tid & 63;
    const int wid  = tid >> 6;
    const int col  = lane & 15;
    const int quad = lane >> 4;
    const int row0 = blockIdx.x * 64 + wid * 16;

    v8s afrag[2];
    #pragma unroll
    for (int kf = 0; kf < 2; ++kf)
        afrag[kf] = cvt8(src_feats + (size_t)(row0 + col) * 64 + kf * 32 + quad * 8);

    v4f acc[8];
    v8s bfrag[8][2];
    #pragma unroll
    for (int ct = 0; ct < 8; ++ct) {
        const int d = (ct & 3) * 16 + col;
        const float* w = (ct < 4 ? fc0_w : fc1_w) + d * 64;
        const float  b = (ct < 4 ? fc0_b : fc1_b)[d];
        acc[ct] = (v4f){b, b, b, b};
        #pragma unroll
        for (int kf = 0; kf < 2; ++kf)
            bfrag[ct][kf] = cvt8(w + kf * 32 + quad * 8);
    }

    #pragma unroll
    for (int kf = 0; kf < 2; ++kf)
        #pragma unroll
        for (int ct = 0; ct < 8; ++ct)
            acc[ct] = __builtin_amdgcn_mfma_f32_16x16x32_bf16(
                afrag[kf], bfrag[ct][kf], acc[ct], 0, 0, 0);

    #pragma unroll
    for (int ct = 0; ct < 8; ++ct) {
        ushort_t* dst = (ct < 4) ? cur0 : cur1;
        const int d = (ct & 3) * 16 + col;
        #pragma unroll
        for (int r = 0; r < 4; ++r) {
            const int n = row0 + quad * 4 + r;
            dst[(size_t)n * 64 + d] = f2bf(acc[ct][r]);
        }
    }
}

// ---------------------------------------------------------------------------
// Kernel 2/3: SA layer. MB=256/S dst points per block, 256 threads (4 waves).
// Prologue: thread t gathers idx/xyz for pair t -> relative coords in LDS.
// Phase A (per mi, batched): S/4 LDS reads -> S/4 cur gathers in flight ->
//   compute (BN folded into p_w, silu, mask) -> x in LDS bf16.
// Phase B: per-wave col-split MFMA over MB independent m's + bn/relu/max_s.
// __launch_bounds__(256,4): LDS caps at 4 blocks/CU anyway; allow ~128 VGPRs
// so the gather batches stay in flight.
// ---------------------------------------------------------------------------
template <int S>
__global__ __launch_bounds__(256, 4) void sa_kernel(
    const float* __restrict__ src_xyz,   // (N,3) f32
    const float* __restrict__ dst_xyz,   // (M,3) f32
    const int*   __restrict__ idx,       // (M,S)
    const int*   __restrict__ empty,     // (M,)
    const float* __restrict__ p_w,       // (64,6)
    const float* __restrict__ p_g,
    const float* __restrict__ p_b,
    const float* __restrict__ m_w,       // (128,64)
    const float* __restrict__ m_g,
    const float* __restrict__ m_b,
    const ushort_t* __restrict__ cur,    // (N,64) bf16
    ushort_t*    __restrict__ f01,       // (M,256) bf16
    int layer_off)
{
    constexpr int MB = 256 / S;          // 16 (S=16) or 8 (S=32)
    constexpr int XP = 72;               // padded row stride (ushorts), 144 B
    constexpr int T  = S / 4;            // pairs per (wave, mi)
    __shared__ ushort_t xlds[MB * S * XP];   // 36864 B
    __shared__ v4f      flds[256];           // 4096 B: (sp-dp).xyz, bitcast(i)

    const int tid  = threadIdx.x;
    const int lane = tid & 63;
    const int wid  = tid >> 6;           // 0..3
    const int m0   = blockIdx.x * MB;

    // ---- prologue: coalesced idx + xyz gathers -> flds (all 256 threads) ----
    {
        const int mi = tid / S;
        const int m  = m0 + mi;
        const int i  = idx[(size_t)m * S + (tid & (S - 1))];
        const float dx = dst_xyz[m * 3 + 0];
        const float dy = dst_xyz[m * 3 + 1];
        const float dz = dst_xyz[m * 3 + 2];
        v4f r;
        r[0] = src_xyz[i * 3 + 0] - dx;
        r[1] = src_xyz[i * 3 + 1] - dy;
        r[2] = src_xyz[i * 3 + 2] - dz;
        r[3] = __int_as_float(i);
        flds[tid] = r;
    }

    // ---- per-lane d-constants (d = lane) ----
    const int d = lane;
    const float pg = p_g[d] * BN_SCALE;
    const float pb = p_b[d];
    const float pwg0 = p_w[d * 6 + 0] * pg;
    const float pwg1 = p_w[d * 6 + 1] * pg;
    const float pwg2 = p_w[d * 6 + 2] * pg;
    const float pd0  = p_w[d * 6 + 3] * pg;
    const float pd1  = p_w[d * 6 + 4] * pg;
    const float pd2  = p_w[d * 6 + 5] * pg;

    // ---- phase-B per-wave constants ----
    const int col  = lane & 15;
    const int quad = lane >> 4;
    v8s bfrag[2][2];                     // [ct][kf]
    float mgv[2], mbv[2];
    #pragma unroll
    for (int c = 0; c < 2; ++c) {
        const int h = (wid * 2 + c) * 16 + col;
        #pragma unroll
        for (int kf = 0; kf < 2; ++kf)
            bfrag[c][kf] = cvt8(m_w + h * 64 + kf * 32 + quad * 8);
        mgv[c] = m_g[h] * BN_SCALE;
        mbv[c] = m_b[h];
    }

    __syncthreads();

    // ================= phase A (batched loads per mi) =================
    const ushort_t* cur_d = cur + d;     // per-lane base (i*64 + d)
    const int tbase = wid * T;
    #pragma unroll
    for (int mi = 0; mi < MB; ++mi) {
        const int m = m0 + mi;
        const float dx = dst_xyz[m * 3 + 0];
        const float dy = dst_xyz[m * 3 + 1];
        const float dz = dst_xyz[m * 3 + 2];
        const float vbase = fmaf(pd0, dx, fmaf(pd1, dy, fmaf(pd2, dz, pb)));
        const int em = empty[m];

        v4f rr[T];
        #pragma unroll
        for (int tt = 0; tt < T; ++tt)
            rr[tt] = flds[mi * S + tbase + tt];      // broadcast b128 reads

        float cf[T];
        #pragma unroll
        for (int tt = 0; tt < T; ++tt)
            cf[tt] = bf2f(cur_d[(size_t)__float_as_int(rr[tt][3]) * 64]);

        #pragma unroll
        for (int tt = 0; tt < T; ++tt) {
            const float v = fmaf(pwg0, rr[tt][0],
                            fmaf(pwg1, rr[tt][1],
                            fmaf(pwg2, rr[tt][2], vbase)));
            const float e  = __expf(-v);
            const float rc = __builtin_amdgcn_rcpf(1.0f + e);
            float x = fmaf(v, rc, cf[tt]);           // silu + cur in one fma
            x = em ? 0.0f : x;
            xlds[(mi * S + tbase + tt) * XP + d] = f2bf(x);
        }
    }
    __syncthreads();

    // ================= phase B: MB independent m's per wave =================
    #pragma unroll
    for (int mi = 0; mi < MB; ++mi) {
        const int m = m0 + mi;
        v4f acc[S / 16][2];
        #pragma unroll
        for (int rt = 0; rt < S / 16; ++rt)
            #pragma unroll
            for (int c = 0; c < 2; ++c)
                acc[rt][c] = (v4f)0.0f;

        #pragma unroll
        for (int rt = 0; rt < S / 16; ++rt) {
            #pragma unroll
            for (int kf = 0; kf < 2; ++kf) {
                const v8s afrag = *(const v8s*)(
                    xlds + ((mi * S + rt * 16 + col)) * XP + kf * 32 + quad * 8);
                acc[rt][0] = __builtin_amdgcn_mfma_f32_16x16x32_bf16(
                    afrag, bfrag[0][kf], acc[rt][0], 0, 0, 0);
                acc[rt][1] = __builtin_amdgcn_mfma_f32_16x16x32_bf16(
                    afrag, bfrag[1][kf], acc[rt][1], 0, 0, 0);
            }
        }

        // epilogue: bn, relu, max over s (C/D layout: col=lane&15, row=quad*4+r)
        float vmax0 = 0.0f, vmax1 = 0.0f;
        #pragma unroll
        for (int c = 0; c < 2; ++c) {
            float vm = 0.0f;   // relu(y)>=0, so 0 is a valid identity
            #pragma unroll
            for (int rt = 0; rt < S / 16; ++rt)
                #pragma unroll
                for (int r = 0; r < 4; ++r) {
                    const float y = fmaf(acc[rt][c][r], mgv[c], mbv[c]);
                    vm = fmaxf(vm, y);
                }
            vm = fmaxf(vm, __shfl_xor(vm, 16));
            vm = fmaxf(vm, __shfl_xor(vm, 32));
            if (c == 0) vmax0 = vm; else vmax1 = vm;
        }
        if (lane < 32) {
            const int c = lane >> 4;
            const float val = (c == 0) ? vmax0 : vmax1;
            f01[m * 256 + layer_off + (wid * 2 + c) * 16 + (lane & 15)] = f2bf(val);
        }
    }
}

// ---------------------------------------------------------------------------
// Kernel 4: out[m][o] = relu(bn(f01[m] . out_w[o])) via MFMA.
// 16 rows/block, 4 waves split the 256 output cols, K=256.
// ---------------------------------------------------------------------------
__global__ __launch_bounds__(256) void out_kernel(
    const ushort_t* __restrict__ f01,     // (M,256) bf16
    const ushort_t* __restrict__ out_wb,  // (256,256) bf16
    const float*    __restrict__ out_g,
    const float*    __restrict__ out_b,
    float*          __restrict__ out)     // (M,256) f32
{
    const int tid  = threadIdx.x;
    const int lane = tid & 63;
    const int wid  = tid >> 6;
    const int col  = lane & 15;
    const int quad = lane >> 4;
    const int m0   = blockIdx.x * 16;

    v8s afrag[8];
    #pragma unroll
    for (int kf = 0; kf < 8; ++kf)
        afrag[kf] = *(const v8s*)(f01 + (size_t)(m0 + col) * 256 + kf * 32 + quad * 8);

    v4f acc[4];
    #pragma unroll
    for (int c = 0; c < 4; ++c) acc[c] = (v4f)0.0f;

    #pragma unroll
    for (int kf = 0; kf < 8; ++kf) {
        #pragma unroll
        for (int c = 0; c < 4; ++c) {
            const int n = (wid * 4 + c) * 16 + col;
            const v8s b = *(const v8s*)(out_wb + (size_t)n * 256 + kf * 32 + quad * 8);
            acc[c] = __builtin_amdgcn_mfma_f32_16x16x32_bf16(afrag[kf], b, acc[c], 0, 0, 0);
        }
    }

    #pragma unroll
    for (int c = 0; c < 4; ++c) {
        const int n  = (wid * 4 + c) * 16 + col;
        const float og = out_g[n] * BN_SCALE;
        const float ob = out_b[n];
        #pragma unroll
        for (int r = 0; r < 4; ++r) {
            float y = fmaf(acc[c][r], og, ob);
            y = fmaxf(y, 0.0f);
            out[(size_t)(m0 + quad * 4 + r) * 256 + n] = y;
        }
    }
}

// ---------------------------------------------------------------------------
extern "C" void kernel_launch(void* const* d_in, const int* in_sizes, int n_in,
                              void* d_out, int out_size, void* d_ws, size_t ws_size,
                              hipStream_t stream)
{
    const float* src_xyz   = (const float*)d_in[0];
    const float* src_feats = (const float*)d_in[1];
    const float* dst_xyz   = (const float*)d_in[2];
    const int*   idx0      = (const int*)d_in[3];
    const int*   idx1      = (const int*)d_in[4];
    const int*   empty0    = (const int*)d_in[5];
    const int*   empty1    = (const int*)d_in[6];
    const float* fc0_w     = (const float*)d_in[7];
    const float* fc0_b     = (const float*)d_in[8];
    const float* p0_w      = (const float*)d_in[9];
    const float* p0_g      = (const float*)d_in[10];
    const float* p0_b      = (const float*)d_in[11];
    const float* m0_w      = (const float*)d_in[12];
    const float* m0_g      = (const float*)d_in[13];
    const float* m0_b      = (const float*)d_in[14];
    const float* fc1_w     = (const float*)d_in[15];
    const float* fc1_b     = (const float*)d_in[16];
    const float* p1_w      = (const float*)d_in[17];
    const float* p1_g      = (const float*)d_in[18];
    const float* p1_b      = (const float*)d_in[19];
    const float* m1_w      = (const float*)d_in[20];
    const float* m1_g      = (const float*)d_in[21];
    const float* m1_b      = (const float*)d_in[22];
    const float* out_w     = (const float*)d_in[23];
    const float* out_g     = (const float*)d_in[24];
    const float* out_b     = (const float*)d_in[25];

    const int N = in_sizes[0] / 3;   // 65536
    const int M = in_sizes[2] / 3;   // 16384

    // ws layout: cur0 | cur1 (N*64 bf16 each) | f01 (M*256 bf16) | out_wb (256*256 bf16)
    ushort_t* cur0   = (ushort_t*)d_ws;
    ushort_t* cur1   = cur0 + (size_t)N * 64;
    ushort_t* f01    = cur1 + (size_t)N * 64;
    ushort_t* out_wb = f01 + (size_t)M * 256;

    convw_kernel<<<64, 256, 0, stream>>>(out_w, out_wb);
    cur_kernel<<<N / 64, 256, 0, stream>>>(src_feats, fc0_w, fc0_b, fc1_w, fc1_b,
                                           cur0, cur1);
    sa_kernel<16><<<M / 16, 256, 0, stream>>>(src_xyz, dst_xyz, idx0, empty0,
                                              p0_w, p0_g, p0_b, m0_w, m0_g, m0_b,
                                              cur0, f01, 0);
    sa_kernel<32><<<M / 8, 256, 0, stream>>>(src_xyz, dst_xyz, idx1, empty1,
                                             p1_w, p1_g, p1_b, m1_w, m1_g, m1_b,
                                             cur1, f01, 128);
    out_kernel<<<M / 16, 256, 0, stream>>>(f01, out_wb, out_g, out_b,
                                           (float*)d_out);
}

// Round 7
// 204.650 us; speedup vs baseline: 1.5554x; 1.0262x over previous
//
#include <hip/hip_runtime.h>

typedef unsigned short ushort_t;
typedef unsigned int uint_t;
typedef __attribute__((ext_vector_type(8))) short v8s;   // 8 x bf16 (4 VGPRs)
typedef __attribute__((ext_vector_type(4))) float v4f;   // MFMA accumulator / float4

#define BN_SCALE 0.9999950000374997f

__device__ __forceinline__ float bf2f(ushort_t u) {
    union { uint_t i; float f; } v;
    v.i = ((uint_t)u) << 16;
    return v.f;
}
__device__ __forceinline__ ushort_t f2bf(float f) {
    union { uint_t i; float f; } v;
    v.f = f;
    uint_t b = v.i;
    b += 0x7fffu + ((b >> 16) & 1u);   // RNE
    return (ushort_t)(b >> 16);
}

__device__ __forceinline__ v8s cvt8(const float* __restrict__ p) {
    v8s f;
    #pragma unroll
    for (int j = 0; j < 8; ++j) f[j] = (short)f2bf(p[j]);
    return f;
}

// ---------------------------------------------------------------------------
// Kernel 0: convert out_w (256x256 f32) -> bf16 in workspace.
// ---------------------------------------------------------------------------
__global__ __launch_bounds__(256) void convw_kernel(
    const float* __restrict__ w, ushort_t* __restrict__ wb)
{
    const int i = (blockIdx.x * 256 + threadIdx.x) * 4;
    const v4f v = *(const v4f*)(w + i);
    ushort_t r0 = f2bf(v[0]), r1 = f2bf(v[1]), r2 = f2bf(v[2]), r3 = f2bf(v[3]);
    uint_t lo = (uint_t)r0 | ((uint_t)r1 << 16);
    uint_t hi = (uint_t)r2 | ((uint_t)r3 << 16);
    *(uint2*)(wb + i) = make_uint2(lo, hi);
}

// ---------------------------------------------------------------------------
// Kernel 1: cur{0,1}[n][d] = src_feats[n] . fc{0,1}_w[d] + fc{0,1}_b[d]
// Pure-MFMA GEMM, no LDS, bias folded into acc init. 64 rows/block.
// ---------------------------------------------------------------------------
__global__ __launch_bounds__(256) void cur_kernel(
    const float* __restrict__ src_feats,                     // (N,64) f32
    const float* __restrict__ fc0_w, const float* __restrict__ fc0_b,
    const float* __restrict__ fc1_w, const float* __restrict__ fc1_b,
    ushort_t* __restrict__ cur0, ushort_t* __restrict__ cur1)
{
    const int tid  = threadIdx.x;
    const int lane = tid & 63;
    const int wid  = tid >> 6;
    const int col  = lane & 15;
    const int quad = lane >> 4;
    const int row0 = blockIdx.x * 64 + wid * 16;

    v8s afrag[2];
    #pragma unroll
    for (int kf = 0; kf < 2; ++kf)
        afrag[kf] = cvt8(src_feats + (size_t)(row0 + col) * 64 + kf * 32 + quad * 8);

    v4f acc[8];
    v8s bfrag[8][2];
    #pragma unroll
    for (int ct = 0; ct < 8; ++ct) {
        const int d = (ct & 3) * 16 + col;
        const float* w = (ct < 4 ? fc0_w : fc1_w) + d * 64;
        const float  b = (ct < 4 ? fc0_b : fc1_b)[d];
        acc[ct] = (v4f){b, b, b, b};
        #pragma unroll
        for (int kf = 0; kf < 2; ++kf)
            bfrag[ct][kf] = cvt8(w + kf * 32 + quad * 8);
    }

    #pragma unroll
    for (int kf = 0; kf < 2; ++kf)
        #pragma unroll
        for (int ct = 0; ct < 8; ++ct)
            acc[ct] = __builtin_amdgcn_mfma_f32_16x16x32_bf16(
                afrag[kf], bfrag[ct][kf], acc[ct], 0, 0, 0);

    #pragma unroll
    for (int ct = 0; ct < 8; ++ct) {
        ushort_t* dst = (ct < 4) ? cur0 : cur1;
        const int d = (ct & 3) * 16 + col;
        #pragma unroll
        for (int r = 0; r < 4; ++r) {
            const int n = row0 + quad * 4 + r;
            dst[(size_t)n * 64 + d] = f2bf(acc[ct][r]);
        }
    }
}

// ---------------------------------------------------------------------------
// SA layer body. 128 pairs/block (MB=128/S m's), 256 threads (4 waves).
// LDS = 20.5 KB -> 6+ blocks/CU (vs 40 KB / 4 blocks before): residency is
// the lever — the kernel is gather-latency-bound, not pipe-bound.
// ---------------------------------------------------------------------------
template <int S>
__device__ __forceinline__ void sa_body(
    const int bid,
    const float* __restrict__ src_xyz,   // (N,3) f32
    const float* __restrict__ dst_xyz,   // (M,3) f32
    const int*   __restrict__ idx,       // (M,S)
    const int*   __restrict__ empty,     // (M,)
    const float* __restrict__ p_w,       // (64,6)
    const float* __restrict__ p_g,
    const float* __restrict__ p_b,
    const float* __restrict__ m_w,       // (128,64)
    const float* __restrict__ m_g,
    const float* __restrict__ m_b,
    const ushort_t* __restrict__ cur,    // (N,64) bf16
    ushort_t*    __restrict__ f01,       // (M,256) bf16
    const int layer_off,
    ushort_t* xlds,                      // [128 * 72]
    v4f*      flds)                      // [128]
{
    constexpr int PAIRS = 128;
    constexpr int MB = PAIRS / S;        // 4 (S=32) or 8 (S=16)
    constexpr int XP = 72;               // padded row stride (ushorts), 144 B
    constexpr int T  = S / 4;            // pairs per (wave, mi)

    const int tid  = threadIdx.x;
    const int lane = tid & 63;
    const int wid  = tid >> 6;           // 0..3
    const int m0   = bid * MB;

    // ---- prologue: coalesced idx + xyz gathers -> flds ----
    if (tid < PAIRS) {
        const int mi = tid / S;
        const int m  = m0 + mi;
        const int i  = idx[(size_t)m * S + (tid & (S - 1))];
        const float dx = dst_xyz[m * 3 + 0];
        const float dy = dst_xyz[m * 3 + 1];
        const float dz = dst_xyz[m * 3 + 2];
        v4f r;
        r[0] = src_xyz[i * 3 + 0] - dx;
        r[1] = src_xyz[i * 3 + 1] - dy;
        r[2] = src_xyz[i * 3 + 2] - dz;
        r[3] = __int_as_float(i);
        flds[tid] = r;
    }

    // ---- per-lane d-constants (d = lane) ----
    const int d = lane;
    const float pg = p_g[d] * BN_SCALE;
    const float pb = p_b[d];
    const float pwg0 = p_w[d * 6 + 0] * pg;
    const float pwg1 = p_w[d * 6 + 1] * pg;
    const float pwg2 = p_w[d * 6 + 2] * pg;
    const float pd0  = p_w[d * 6 + 3] * pg;
    const float pd1  = p_w[d * 6 + 4] * pg;
    const float pd2  = p_w[d * 6 + 5] * pg;

    __syncthreads();

    // ================= phase A (batched loads per mi) =================
    const ushort_t* cur_d = cur + d;     // per-lane base (i*64 + d)
    const int tbase = wid * T;
    #pragma unroll
    for (int mi = 0; mi < MB; ++mi) {
        const int m = m0 + mi;
        const float dx = dst_xyz[m * 3 + 0];
        const float dy = dst_xyz[m * 3 + 1];
        const float dz = dst_xyz[m * 3 + 2];
        const float vbase = fmaf(pd0, dx, fmaf(pd1, dy, fmaf(pd2, dz, pb)));
        const int em = empty[m];

        v4f rr[T];
        #pragma unroll
        for (int tt = 0; tt < T; ++tt)
            rr[tt] = flds[mi * S + tbase + tt];      // broadcast b128 reads

        ushort_t cfu[T];
        #pragma unroll
        for (int tt = 0; tt < T; ++tt)
            cfu[tt] = cur_d[(size_t)__float_as_int(rr[tt][3]) * 64];

        #pragma unroll
        for (int tt = 0; tt < T; ++tt) {
            const float v = fmaf(pwg0, rr[tt][0],
                            fmaf(pwg1, rr[tt][1],
                            fmaf(pwg2, rr[tt][2], vbase)));
            const float rc = __builtin_amdgcn_rcpf(1.0f + __expf(-v));
            float x = fmaf(v, rc, bf2f(cfu[tt]));    // silu + cur in one fma
            x = em ? 0.0f : x;
            xlds[(mi * S + tbase + tt) * XP + d] = f2bf(x);
        }
    }

    // ---- phase-B per-wave constants (loaded after phase-A VGPR peak) ----
    const int col  = lane & 15;
    const int quad = lane >> 4;
    v8s bfrag[2][2];                     // [ct][kf]
    float mgv[2], mbv[2];
    #pragma unroll
    for (int c = 0; c < 2; ++c) {
        const int h = (wid * 2 + c) * 16 + col;
        #pragma unroll
        for (int kf = 0; kf < 2; ++kf)
            bfrag[c][kf] = cvt8(m_w + h * 64 + kf * 32 + quad * 8);
        mgv[c] = m_g[h] * BN_SCALE;
        mbv[c] = m_b[h];
    }

    __syncthreads();

    // ================= phase B: MB independent m's per wave =================
    #pragma unroll
    for (int mi = 0; mi < MB; ++mi) {
        const int m = m0 + mi;
        v4f acc[S / 16][2];
        #pragma unroll
        for (int rt = 0; rt < S / 16; ++rt)
            #pragma unroll
            for (int c = 0; c < 2; ++c)
                acc[rt][c] = (v4f)0.0f;

        #pragma unroll
        for (int rt = 0; rt < S / 16; ++rt) {
            #pragma unroll
            for (int kf = 0; kf < 2; ++kf) {
                const v8s afrag = *(const v8s*)(
                    xlds + ((mi * S + rt * 16 + col)) * XP + kf * 32 + quad * 8);
                acc[rt][0] = __builtin_amdgcn_mfma_f32_16x16x32_bf16(
                    afrag, bfrag[0][kf], acc[rt][0], 0, 0, 0);
                acc[rt][1] = __builtin_amdgcn_mfma_f32_16x16x32_bf16(
                    afrag, bfrag[1][kf], acc[rt][1], 0, 0, 0);
            }
        }

        // epilogue: bn, relu, max over s (C/D layout: col=lane&15, row=quad*4+r)
        float vmax0 = 0.0f, vmax1 = 0.0f;
        #pragma unroll
        for (int c = 0; c < 2; ++c) {
            float vm = 0.0f;   // relu(y)>=0, so 0 is a valid identity
            #pragma unroll
            for (int rt = 0; rt < S / 16; ++rt)
                #pragma unroll
                for (int r = 0; r < 4; ++r) {
                    const float y = fmaf(acc[rt][c][r], mgv[c], mbv[c]);
                    vm = fmaxf(vm, y);
                }
            vm = fmaxf(vm, __shfl_xor(vm, 16));
            vm = fmaxf(vm, __shfl_xor(vm, 32));
            if (c == 0) vmax0 = vm; else vmax1 = vm;
        }
        if (lane < 32) {
            const int c = lane >> 4;
            const float val = (c == 0) ? vmax0 : vmax1;
            f01[m * 256 + layer_off + (wid * 2 + c) * 16 + (lane & 15)] = f2bf(val);
        }
    }
}

// ---------------------------------------------------------------------------
// Kernel 2: fused SA layers. Blocks [0, G32) run layer 1 (S=32), blocks
// [G32, G32+G16) run layer 0 (S=16). Heterogeneous blocks co-resident on a
// CU fill each other's gather-stall slots.
// ---------------------------------------------------------------------------
__global__ __launch_bounds__(256, 6) void sa_fused_kernel(
    const float* __restrict__ src_xyz, const float* __restrict__ dst_xyz,
    const int* __restrict__ idx0, const int* __restrict__ empty0,
    const float* __restrict__ p0_w, const float* __restrict__ p0_g, const float* __restrict__ p0_b,
    const float* __restrict__ m0_w, const float* __restrict__ m0_g, const float* __restrict__ m0_b,
    const ushort_t* __restrict__ cur0,
    const int* __restrict__ idx1, const int* __restrict__ empty1,
    const float* __restrict__ p1_w, const float* __restrict__ p1_g, const float* __restrict__ p1_b,
    const float* __restrict__ m1_w, const float* __restrict__ m1_g, const float* __restrict__ m1_b,
    const ushort_t* __restrict__ cur1,
    ushort_t* __restrict__ f01, const int G32)
{
    __shared__ ushort_t xlds[128 * 72];  // 18432 B
    __shared__ v4f      flds[128];       //  2048 B

    const int b = blockIdx.x;
    if (b < G32)
        sa_body<32>(b, src_xyz, dst_xyz, idx1, empty1, p1_w, p1_g, p1_b,
                    m1_w, m1_g, m1_b, cur1, f01, 128, xlds, flds);
    else
        sa_body<16>(b - G32, src_xyz, dst_xyz, idx0, empty0, p0_w, p0_g, p0_b,
                    m0_w, m0_g, m0_b, cur0, f01, 0, xlds, flds);
}

// ---------------------------------------------------------------------------
// Kernel 4: out[m][o] = relu(bn(f01[m] . out_w[o])) via MFMA.
// 16 rows/block, 4 waves split the 256 output cols, K=256.
// ---------------------------------------------------------------------------
__global__ __launch_bounds__(256) void out_kernel(
    const ushort_t* __restrict__ f01,     // (M,256) bf16
    const ushort_t* __restrict__ out_wb,  // (256,256) bf16
    const float*    __restrict__ out_g,
    const float*    __restrict__ out_b,
    float*          __restrict__ out)     // (M,256) f32
{
    const int tid  = threadIdx.x;
    const int lane = tid & 63;
    const int wid  = tid >> 6;
    const int col  = lane & 15;
    const int quad = lane >> 4;
    const int m0   = blockIdx.x * 16;

    v8s afrag[8];
    #pragma unroll
    for (int kf = 0; kf < 8; ++kf)
        afrag[kf] = *(const v8s*)(f01 + (size_t)(m0 + col) * 256 + kf * 32 + quad * 8);

    v4f acc[4];
    #pragma unroll
    for (int c = 0; c < 4; ++c) acc[c] = (v4f)0.0f;

    #pragma unroll
    for (int kf = 0; kf < 8; ++kf) {
        #pragma unroll
        for (int c = 0; c < 4; ++c) {
            const int n = (wid * 4 + c) * 16 + col;
            const v8s b = *(const v8s*)(out_wb + (size_t)n * 256 + kf * 32 + quad * 8);
            acc[c] = __builtin_amdgcn_mfma_f32_16x16x32_bf16(afrag[kf], b, acc[c], 0, 0, 0);
        }
    }

    #pragma unroll
    for (int c = 0; c < 4; ++c) {
        const int n  = (wid * 4 + c) * 16 + col;
        const float og = out_g[n] * BN_SCALE;
        const float ob = out_b[n];
        #pragma unroll
        for (int r = 0; r < 4; ++r) {
            float y = fmaf(acc[c][r], og, ob);
            y = fmaxf(y, 0.0f);
            out[(size_t)(m0 + quad * 4 + r) * 256 + n] = y;
        }
    }
}

// ---------------------------------------------------------------------------
extern "C" void kernel_launch(void* const* d_in, const int* in_sizes, int n_in,
                              void* d_out, int out_size, void* d_ws, size_t ws_size,
                              hipStream_t stream)
{
    const float* src_xyz   = (const float*)d_in[0];
    const float* src_feats = (const float*)d_in[1];
    const float* dst_xyz   = (const float*)d_in[2];
    const int*   idx0      = (const int*)d_in[3];
    const int*   idx1      = (const int*)d_in[4];
    const int*   empty0    = (const int*)d_in[5];
    const int*   empty1    = (const int*)d_in[6];
    const float* fc0_w     = (const float*)d_in[7];
    const float* fc0_b     = (const float*)d_in[8];
    const float* p0_w      = (const float*)d_in[9];
    const float* p0_g      = (const float*)d_in[10];
    const float* p0_b      = (const float*)d_in[11];
    const float* m0_w      = (const float*)d_in[12];
    const float* m0_g      = (const float*)d_in[13];
    const float* m0_b      = (const float*)d_in[14];
    const float* fc1_w     = (const float*)d_in[15];
    const float* fc1_b     = (const float*)d_in[16];
    const float* p1_w      = (const float*)d_in[17];
    const float* p1_g      = (const float*)d_in[18];
    const float* p1_b      = (const float*)d_in[19];
    const float* m1_w      = (const float*)d_in[20];
    const float* m1_g      = (const float*)d_in[21];
    const float* m1_b      = (const float*)d_in[22];
    const float* out_w     = (const float*)d_in[23];
    const float* out_g     = (const float*)d_in[24];
    const float* out_b     = (const float*)d_in[25];

    const int N = in_sizes[0] / 3;   // 65536
    const int M = in_sizes[2] / 3;   // 16384

    // ws layout: cur0 | cur1 (N*64 bf16 each) | f01 (M*256 bf16) | out_wb (256*256 bf16)
    ushort_t* cur0   = (ushort_t*)d_ws;
    ushort_t* cur1   = cur0 + (size_t)N * 64;
    ushort_t* f01    = cur1 + (size_t)N * 64;
    ushort_t* out_wb = f01 + (size_t)M * 256;

    const int G32 = M / 4;   // sa32: MB=4
    const int G16 = M / 8;   // sa16: MB=8

    convw_kernel<<<64, 256, 0, stream>>>(out_w, out_wb);
    cur_kernel<<<N / 64, 256, 0, stream>>>(src_feats, fc0_w, fc0_b, fc1_w, fc1_b,
                                           cur0, cur1);
    sa_fused_kernel<<<G32 + G16, 256, 0, stream>>>(
        src_xyz, dst_xyz,
        idx0, empty0, p0_w, p0_g, p0_b, m0_w, m0_g, m0_b, cur0,
        idx1, empty1, p1_w, p1_g, p1_b, m1_w, m1_g, m1_b, cur1,
        f01, G32);
    out_kernel<<<M / 16, 256, 0, stream>>>(f01, out_wb, out_g, out_b,
                                           (float*)d_out);
}